// Round 7
// baseline (341.368 us; speedup 1.0000x reference)
//
#include <hip/hip_runtime.h>
#include <hip/hip_bf16.h>

// ---------------------------------------------------------------------------
// GraphExpert: per-node expert MLPs (16 nodes, 2048 batch, 512 hid) + gating.
// fp32 global I/O, bf16 MFMA compute.
// R7: gemm1 = R4-exact staging (plain fp32 loads -> cvt in staging phase ->
// swizzled ds_write; B via global_load_lds) + fused gating (R5/R6-proven
// fragment reuse). Standalone gating kernel deleted. gemm2 = R4 verbatim.
// Workspace = proven 52.56 MB envelope.
// ---------------------------------------------------------------------------

typedef __attribute__((ext_vector_type(8))) short bf16x8;   // 8 bf16 = 4 VGPRs
typedef __attribute__((ext_vector_type(4))) float f32x4;    // MFMA C/D frag

// workspace layout (bytes) — identical to R2/R4 (proven safe)
#define OFF_W1T  (0u)          // bf16 [16][512][512]  (8 MB)
#define OFF_W2T  (8388608u)    // bf16 [16][512][512]  (8 MB)
#define OFF_H    (16777216u)   // bf16 [2048][16][512] (33.55 MB)
#define OFF_PART (50331648u)   // fp32 [16][2048][16]  (2 MB)
#define OFF_PROB (52428800u)   // fp32 [2048][16]      (128 KB)

__device__ __forceinline__ void gl2lds16(const void* g, void* l) {
  __builtin_amdgcn_global_load_lds(
      (const __attribute__((address_space(1))) void*)g,
      (__attribute__((address_space(3))) void*)l, 16, 0, 0);
}

// ------------- weight transpose + cvt: Wt[n][h][k] = bf16(W[n][k][h]) -------
__global__ void transpose_kernel(const float* __restrict__ W1,
                                 const float* __restrict__ W2,
                                 __hip_bfloat16* __restrict__ W1t,
                                 __hip_bfloat16* __restrict__ W2t) {
  __shared__ __hip_bfloat16 tile[32][33];
  const int n = blockIdx.z & 15;
  const float* src = (blockIdx.z >> 4) ? W2 : W1;
  __hip_bfloat16* dst = (blockIdx.z >> 4) ? W2t : W1t;
  src += (size_t)n * 262144;
  dst += (size_t)n * 262144;
  const int h0 = blockIdx.x * 32, k0 = blockIdx.y * 32;
  const int tx = threadIdx.x, ty = threadIdx.y; // 32 x 8
#pragma unroll
  for (int i = 0; i < 32; i += 8)
    tile[ty + i][tx] = __float2bfloat16(src[(size_t)(k0 + ty + i) * 512 + h0 + tx]);
  __syncthreads();
#pragma unroll
  for (int i = 0; i < 32; i += 8)
    dst[(size_t)(h0 + ty + i) * 512 + k0 + tx] = tile[tx][ty + i];
}

// ---------------- softmax: probs fp32 (ws) + expert_probs fp32 (out) --------
__global__ void softmax_kernel(const float* __restrict__ partial,
                               const float* __restrict__ bg,
                               float* __restrict__ probs,
                               float* __restrict__ probs_out) {
  const int r = blockIdx.x * 256 + threadIdx.x; // 0..2047
  float s[16];
#pragma unroll
  for (int j = 0; j < 16; j++) s[j] = 0.f;
  for (int nn = 0; nn < 16; nn++) {
    const float4* p = (const float4*)(partial + ((size_t)nn * 2048 + r) * 16);
#pragma unroll
    for (int c = 0; c < 4; c++) {
      float4 v = p[c];
      s[c * 4 + 0] += v.x; s[c * 4 + 1] += v.y;
      s[c * 4 + 2] += v.z; s[c * 4 + 3] += v.w;
    }
  }
  float mx = -1e30f;
#pragma unroll
  for (int j = 0; j < 16; j++) { s[j] += bg[j]; mx = fmaxf(mx, s[j]); }
  float sum = 0.f;
#pragma unroll
  for (int j = 0; j < 16; j++) { s[j] = __expf(s[j] - mx); sum += s[j]; }
  float inv = 1.f / sum;
#pragma unroll
  for (int j = 0; j < 16; j++) s[j] *= inv;
  float4* pw = (float4*)(probs + (size_t)r * 16);
  float4* ow = (float4*)(probs_out + (size_t)r * 16);
#pragma unroll
  for (int c = 0; c < 4; c++) {
    float4 v = make_float4(s[c*4], s[c*4+1], s[c*4+2], s[c*4+3]);
    pw[c] = v; ow[c] = v;
  }
}

// block-id remap: the 4 nblk siblings sharing one A-strip sit at bids
// b, b+8, b+16, b+24 (same bid%8 -> same XCD) for L2 reuse of the A strip.
__device__ __forceinline__ void decode_bid(int bid, int& nblk, int& mblk, int& n) {
  int x8 = bid & 7;
  nblk = (bid >> 3) & 3;
  int pair = (bid >> 5) * 8 + x8; // 0..255
  mblk = pair >> 4;
  n = pair & 15;
}

// ---------------- GEMM1 (+fused gating): h = bf16(relu(graphs@W1t + b1)) ----
// BK=64; XOR-swizzled LDS: LDS[row][slot s] = Gchunk[s ^ (row&7)] (16B chunks)
// A: plain fp32 loads -> cvt (staging phase, short-lived regs) -> ds_write.
// B: global_load_lds. nblk==0 blocks also accumulate gating partials from the
// av[] fragments already in registers (R5/R6-proven).
__global__ __launch_bounds__(256, 4) void gemm1_kernel(
    const float* __restrict__ graphs,
    const __hip_bfloat16* __restrict__ W1t,
    const float* __restrict__ Wg,
    const float* __restrict__ b1,
    __hip_bfloat16* __restrict__ h,
    float* __restrict__ partial) {
  __shared__ char smem[39168]; // A 16K @0, B 16K @16384, (epi 4x9216 @0),
                               // WgT 16 rows x 144 B @36864
  const int tid = threadIdx.x, lane = tid & 63, wave = tid >> 6;
  int nblk, mblk, n;
  decode_bid(blockIdx.x, nblk, mblk, n);
  const int wm = (wave >> 1) * 64, wn = (wave & 1) * 64;
  const int q = lane >> 4, l15 = lane & 15;
  const int lrow = lane >> 3, lcol = lane & 7;
  const int swz = (lcol ^ lrow) * 8;  // B-side: global chunk for LDS slot lcol
  const int xr = l15 & 7;             // read-side row&7
  const int arow = tid >> 1, ahalf = (tid & 1) * 32; // A staging: row, col-half
  const int arx = arow & 7;
  const int wk = tid >> 2, wj = (tid & 3) * 4;       // Wg staging
  const bool do_gate = (nblk == 0);
  const int gt0 = (wave & 1) * 2; // gating uses av[gt0], av[gt0+1]

  const float* Ag = graphs + (size_t)(mblk * 128) * 8192 + n * 512;
  const __hip_bfloat16* Bg = W1t + (size_t)n * 262144 + (size_t)(nblk * 128) * 512;
  const float* Wgg = Wg + (size_t)(n * 512) * 16;

  f32x4 acc[4][4] = {};
  f32x4 accg[2] = {};
  for (int ks = 0; ks < 8; ks++) {
    const int k0 = ks * 64;
    // ---- A: 32 fp32 per thread -> cvt -> 4 swizzled ds_write_b128
    const float* asrc = Ag + (size_t)arow * 8192 + k0 + ahalf;
    float f[32];
#pragma unroll
    for (int j = 0; j < 8; j++) *(float4*)(f + j * 4) = *(const float4*)(asrc + j * 4);
    __hip_bfloat16 t[32];
#pragma unroll
    for (int e = 0; e < 32; e++) t[e] = __float2bfloat16(f[e]);
    char* abase = smem + arow * 128;
#pragma unroll
    for (int j = 0; j < 4; j++) {
      int c = (ahalf >> 3) + j; // global chunk index 0..7
      *(bf16x8*)(abase + ((c ^ arx) * 16)) = *(const bf16x8*)(t + j * 8);
    }
    // ---- B: async global->LDS, swizzled on the global side
#pragma unroll
    for (int i = 0; i < 4; i++) {
      const int r = i * 32 + wave * 8 + lrow;
      gl2lds16(Bg + (size_t)r * 512 + k0 + swz,
               smem + 16384 + i * 4096 + wave * 1024 + lane * 16);
    }
    // ---- WgT slice for this k-chunk (gating blocks only)
    if (do_gate) {
      float4 wgq = *(const float4*)(Wgg + (size_t)(k0 + wk) * 16 + wj);
      __hip_bfloat16 wt[4] = {__float2bfloat16(wgq.x), __float2bfloat16(wgq.y),
                              __float2bfloat16(wgq.z), __float2bfloat16(wgq.w)};
#pragma unroll
      for (int i = 0; i < 4; i++)
        *(__hip_bfloat16*)(smem + 36864 + (wj + i) * 144 + wk * 2) = wt[i];
    }
    __syncthreads();
    // ---- MFMA phase for tile ks
#pragma unroll
    for (int hh = 0; hh < 2; hh++) {
      const int co = ((q + hh * 4) ^ xr) * 16;
      bf16x8 av[4], bv[4];
#pragma unroll
      for (int im = 0; im < 4; im++)
        av[im] = *(const bf16x8*)(smem + (wm + im * 16 + l15) * 128 + co);
#pragma unroll
      for (int in = 0; in < 4; in++)
        bv[in] = *(const bf16x8*)(smem + 16384 + (wn + in * 16 + l15) * 128 + co);
#pragma unroll
      for (int im = 0; im < 4; im++)
#pragma unroll
        for (int in = 0; in < 4; in++)
          acc[im][in] = __builtin_amdgcn_mfma_f32_16x16x32_bf16(av[im], bv[in], acc[im][in], 0, 0, 0);
      if (do_gate) {
        bf16x8 wv = *(const bf16x8*)(smem + 36864 + l15 * 144 + (q + hh * 4) * 16);
        accg[0] = __builtin_amdgcn_mfma_f32_16x16x32_bf16(av[gt0], wv, accg[0], 0, 0, 0);
        accg[1] = __builtin_amdgcn_mfma_f32_16x16x32_bf16(av[gt0 + 1], wv, accg[1], 0, 0, 0);
      }
    }
    __syncthreads();
  }

  // ---- gating epilogue: partial[n][row][j]  (R5/R6-proven)
  if (do_gate) {
#pragma unroll
    for (int t2 = 0; t2 < 2; t2++)
#pragma unroll
      for (int r = 0; r < 4; r++) {
        int row = mblk * 128 + wave * 32 + t2 * 16 + q * 4 + r;
        partial[((size_t)n * 2048 + row) * 16 + l15] = accg[t2][r];
      }
  }

  // ---- main epilogue: bias+relu, repack via LDS (stride 144 B), coalesced store
  float bias[4];
#pragma unroll
  for (int in = 0; in < 4; in++)
    bias[in] = b1[n * 512 + nblk * 128 + wn + in * 16 + l15];
  char* epi = smem + wave * 9216;
#pragma unroll
  for (int im = 0; im < 4; im++)
#pragma unroll
    for (int in = 0; in < 4; in++)
#pragma unroll
      for (int r = 0; r < 4; r++) {
        float v = acc[im][in][r] + bias[in];
        v = fmaxf(v, 0.f);
        int rl = im * 16 + q * 4 + r;
        int cl = in * 16 + l15;
        *(__hip_bfloat16*)(epi + rl * 144 + cl * 2) = __float2bfloat16(v);
      }
  __syncthreads();
  __hip_bfloat16* Hg = h + (size_t)(mblk * 128 + wm) * 8192 + n * 512 + nblk * 128 + wn;
#pragma unroll
  for (int it = 0; it < 8; it++) {
    int rl = it * 8 + (lane >> 3);
    int cl = (lane & 7) * 8;
    bf16x8 v = *(const bf16x8*)(epi + rl * 144 + cl * 2);
    *(bf16x8*)(Hg + (size_t)rl * 8192 + cl) = v;
  }
}

// ---------------- GEMM2 + weighted combine (fp32 out) — R4-proven -----------
__global__ __launch_bounds__(256, 4) void gemm2_kernel(
    const __hip_bfloat16* __restrict__ hbuf,
    const __hip_bfloat16* __restrict__ W2t,
    const float* __restrict__ b2,
    const float* __restrict__ probs,
    float* __restrict__ out) {
  __shared__ char smem[32768];
  const int tid = threadIdx.x, lane = tid & 63, wave = tid >> 6;
  int nblk, mblk, n;
  decode_bid(blockIdx.x, nblk, mblk, n);
  const int wm = (wave >> 1) * 64, wn = (wave & 1) * 64;
  const int q = lane >> 4, l15 = lane & 15;
  const int lrow = lane >> 3, lcol = lane & 7;
  const int swz = (lcol ^ lrow) * 8;
  const int xr = l15 & 7;

  const __hip_bfloat16* Ag = hbuf + (size_t)(mblk * 128) * 8192 + n * 512;
  const __hip_bfloat16* Bg = W2t + (size_t)n * 262144 + (size_t)(nblk * 128) * 512;

  f32x4 acc[4][4] = {};
  for (int ks = 0; ks < 8; ks++) {
    const int k0 = ks * 64;
#pragma unroll
    for (int i = 0; i < 4; i++) {
      const int r = i * 32 + wave * 8 + lrow;
      gl2lds16(Ag + (size_t)r * 8192 + k0 + swz, smem + i * 4096 + wave * 1024 + lane * 16);
      gl2lds16(Bg + (size_t)r * 512 + k0 + swz,
               smem + 16384 + i * 4096 + wave * 1024 + lane * 16);
    }
    __syncthreads();
#pragma unroll
    for (int hh = 0; hh < 2; hh++) {
      const int co = ((q + hh * 4) ^ xr) * 16;
      bf16x8 av[4], bv[4];
#pragma unroll
      for (int im = 0; im < 4; im++)
        av[im] = *(const bf16x8*)(smem + (wm + im * 16 + l15) * 128 + co);
#pragma unroll
      for (int in = 0; in < 4; in++)
        bv[in] = *(const bf16x8*)(smem + 16384 + (wn + in * 16 + l15) * 128 + co);
#pragma unroll
      for (int im = 0; im < 4; im++)
#pragma unroll
        for (int in = 0; in < 4; in++)
          acc[im][in] = __builtin_amdgcn_mfma_f32_16x16x32_bf16(av[im], bv[in], acc[im][in], 0, 0, 0);
    }
    __syncthreads();
  }

  float bias[4];
#pragma unroll
  for (int in = 0; in < 4; in++)
    bias[in] = b2[n * 512 + nblk * 128 + wn + in * 16 + l15];
  float* comb = (float*)smem; // [128][8] fp32 (staging LDS reused)
#pragma unroll
  for (int im = 0; im < 4; im++)
#pragma unroll
    for (int r = 0; r < 4; r++) {
      int rl = wm + im * 16 + q * 4 + r; // block-local row 0..127
      float pv = probs[(size_t)(mblk * 128 + rl) * 16 + l15];
#pragma unroll
      for (int in = 0; in < 4; in++) {
        float v = (acc[im][in][r] + bias[in]) * pv;
        v += __shfl_xor(v, 1);
        v += __shfl_xor(v, 2);
        v += __shfl_xor(v, 4);
        v += __shfl_xor(v, 8);
        if (l15 == 0) comb[rl * 8 + (wn >> 4) + in] = v;
      }
    }
  __syncthreads();
  if (tid < 128) {
    float4 v0 = *(const float4*)(comb + tid * 8);
    float4 v1 = *(const float4*)(comb + tid * 8 + 4);
    float* orow = out + (size_t)(mblk * 128 + tid) * 512 + n * 32 + nblk * 8;
    *(float4*)orow = v0;
    *(float4*)(orow + 4) = v1;
  }
}

// ---------------------------------------------------------------------------
extern "C" void kernel_launch(void* const* d_in, const int* in_sizes, int n_in,
                              void* d_out, int out_size, void* d_ws, size_t ws_size,
                              hipStream_t stream) {
  const float* graphs = (const float*)d_in[0];
  const float* W1 = (const float*)d_in[1];
  const float* b1 = (const float*)d_in[2];
  const float* W2 = (const float*)d_in[3];
  const float* b2 = (const float*)d_in[4];
  const float* Wg = (const float*)d_in[5];
  const float* bg = (const float*)d_in[6];
  float* out = (float*)d_out;

  char* ws = (char*)d_ws;
  __hip_bfloat16* W1t = (__hip_bfloat16*)(ws + OFF_W1T);
  __hip_bfloat16* W2t = (__hip_bfloat16*)(ws + OFF_W2T);
  __hip_bfloat16* hb  = (__hip_bfloat16*)(ws + OFF_H);
  float* partial = (float*)(ws + OFF_PART);
  float* probs   = (float*)(ws + OFF_PROB);

  transpose_kernel<<<dim3(16, 16, 32), dim3(32, 8), 0, stream>>>(W1, W2, W1t, W2t);
  gemm1_kernel<<<1024, 256, 0, stream>>>(graphs, W1t, Wg, b1, hb, partial);
  softmax_kernel<<<8, 256, 0, stream>>>(partial, bg, probs, out + 2048 * 512);
  gemm2_kernel<<<1024, 256, 0, stream>>>(hb, W2t, b2, probs, out);
}

// Round 8
// 306.928 us; speedup vs baseline: 1.1122x; 1.1122x over previous
//
#include <hip/hip_runtime.h>
#include <hip/hip_bf16.h>

// ---------------------------------------------------------------------------
// GraphExpert: per-node expert MLPs (16 nodes, 2048 batch, 512 hid) + gating.
// fp32 global I/O, bf16 MFMA compute.
// R8: R7 minus the register spill. gemm1 = R4-exact staging + fused gating,
// but __launch_bounds__(256,3) (170-reg budget: 72 acc/accg AGPRs + staging
// VGPRs fit, no spill) and A-staging split into two 16-float chunks to halve
// peak staging live-set. gemm2 = R4 verbatim. Workspace = proven 52.56 MB.
// ---------------------------------------------------------------------------

typedef __attribute__((ext_vector_type(8))) short bf16x8;   // 8 bf16 = 4 VGPRs
typedef __attribute__((ext_vector_type(4))) float f32x4;    // MFMA C/D frag

// workspace layout (bytes) — identical to R2/R4 (proven safe)
#define OFF_W1T  (0u)          // bf16 [16][512][512]  (8 MB)
#define OFF_W2T  (8388608u)    // bf16 [16][512][512]  (8 MB)
#define OFF_H    (16777216u)   // bf16 [2048][16][512] (33.55 MB)
#define OFF_PART (50331648u)   // fp32 [16][2048][16]  (2 MB)
#define OFF_PROB (52428800u)   // fp32 [2048][16]      (128 KB)

__device__ __forceinline__ void gl2lds16(const void* g, void* l) {
  __builtin_amdgcn_global_load_lds(
      (const __attribute__((address_space(1))) void*)g,
      (__attribute__((address_space(3))) void*)l, 16, 0, 0);
}

// ------------- weight transpose + cvt: Wt[n][h][k] = bf16(W[n][k][h]) -------
__global__ void transpose_kernel(const float* __restrict__ W1,
                                 const float* __restrict__ W2,
                                 __hip_bfloat16* __restrict__ W1t,
                                 __hip_bfloat16* __restrict__ W2t) {
  __shared__ __hip_bfloat16 tile[32][33];
  const int n = blockIdx.z & 15;
  const float* src = (blockIdx.z >> 4) ? W2 : W1;
  __hip_bfloat16* dst = (blockIdx.z >> 4) ? W2t : W1t;
  src += (size_t)n * 262144;
  dst += (size_t)n * 262144;
  const int h0 = blockIdx.x * 32, k0 = blockIdx.y * 32;
  const int tx = threadIdx.x, ty = threadIdx.y; // 32 x 8
#pragma unroll
  for (int i = 0; i < 32; i += 8)
    tile[ty + i][tx] = __float2bfloat16(src[(size_t)(k0 + ty + i) * 512 + h0 + tx]);
  __syncthreads();
#pragma unroll
  for (int i = 0; i < 32; i += 8)
    dst[(size_t)(h0 + ty + i) * 512 + k0 + tx] = tile[tx][ty + i];
}

// ---------------- softmax: probs fp32 (ws) + expert_probs fp32 (out) --------
__global__ void softmax_kernel(const float* __restrict__ partial,
                               const float* __restrict__ bg,
                               float* __restrict__ probs,
                               float* __restrict__ probs_out) {
  const int r = blockIdx.x * 256 + threadIdx.x; // 0..2047
  float s[16];
#pragma unroll
  for (int j = 0; j < 16; j++) s[j] = 0.f;
  for (int nn = 0; nn < 16; nn++) {
    const float4* p = (const float4*)(partial + ((size_t)nn * 2048 + r) * 16);
#pragma unroll
    for (int c = 0; c < 4; c++) {
      float4 v = p[c];
      s[c * 4 + 0] += v.x; s[c * 4 + 1] += v.y;
      s[c * 4 + 2] += v.z; s[c * 4 + 3] += v.w;
    }
  }
  float mx = -1e30f;
#pragma unroll
  for (int j = 0; j < 16; j++) { s[j] += bg[j]; mx = fmaxf(mx, s[j]); }
  float sum = 0.f;
#pragma unroll
  for (int j = 0; j < 16; j++) { s[j] = __expf(s[j] - mx); sum += s[j]; }
  float inv = 1.f / sum;
#pragma unroll
  for (int j = 0; j < 16; j++) s[j] *= inv;
  float4* pw = (float4*)(probs + (size_t)r * 16);
  float4* ow = (float4*)(probs_out + (size_t)r * 16);
#pragma unroll
  for (int c = 0; c < 4; c++) {
    float4 v = make_float4(s[c*4], s[c*4+1], s[c*4+2], s[c*4+3]);
    pw[c] = v; ow[c] = v;
  }
}

// block-id remap: the 4 nblk siblings sharing one A-strip sit at bids
// b, b+8, b+16, b+24 (same bid%8 -> same XCD) for L2 reuse of the A strip.
__device__ __forceinline__ void decode_bid(int bid, int& nblk, int& mblk, int& n) {
  int x8 = bid & 7;
  nblk = (bid >> 3) & 3;
  int pair = (bid >> 5) * 8 + x8; // 0..255
  mblk = pair >> 4;
  n = pair & 15;
}

// ---------------- GEMM1 (+fused gating): h = bf16(relu(graphs@W1t + b1)) ----
// BK=64; XOR-swizzled LDS: LDS[row][slot s] = Gchunk[s ^ (row&7)] (16B chunks)
// A: plain fp32 loads -> cvt (staging phase, two 16-float chunks, short-lived
// regs) -> swizzled ds_write. B: global_load_lds. nblk==0 blocks accumulate
// gating partials from the av[] fragments already in registers (proven).
// launch_bounds (256,3): 170-reg budget so 72 accum AGPRs + staging never
// spill (R7's (256,4)=128 cap caused a 230 MB scratch round-trip).
__global__ __launch_bounds__(256, 3) void gemm1_kernel(
    const float* __restrict__ graphs,
    const __hip_bfloat16* __restrict__ W1t,
    const float* __restrict__ Wg,
    const float* __restrict__ b1,
    __hip_bfloat16* __restrict__ h,
    float* __restrict__ partial) {
  __shared__ char smem[39168]; // A 16K @0, B 16K @16384, (epi 4x9216 @0),
                               // WgT 16 rows x 144 B @36864
  const int tid = threadIdx.x, lane = tid & 63, wave = tid >> 6;
  int nblk, mblk, n;
  decode_bid(blockIdx.x, nblk, mblk, n);
  const int wm = (wave >> 1) * 64, wn = (wave & 1) * 64;
  const int q = lane >> 4, l15 = lane & 15;
  const int lrow = lane >> 3, lcol = lane & 7;
  const int swz = (lcol ^ lrow) * 8;  // B-side: global chunk for LDS slot lcol
  const int xr = l15 & 7;             // read-side row&7
  const int arow = tid >> 1, ahalf = (tid & 1) * 32; // A staging: row, col-half
  const int arx = arow & 7;
  const int wk = tid >> 2, wj = (tid & 3) * 4;       // Wg staging
  const bool do_gate = (nblk == 0);
  const int gt0 = (wave & 1) * 2; // gating uses av[gt0], av[gt0+1]

  const float* Ag = graphs + (size_t)(mblk * 128) * 8192 + n * 512;
  const __hip_bfloat16* Bg = W1t + (size_t)n * 262144 + (size_t)(nblk * 128) * 512;
  const float* Wgg = Wg + (size_t)(n * 512) * 16;

  f32x4 acc[4][4] = {};
  f32x4 accg[2] = {};
  for (int ks = 0; ks < 8; ks++) {
    const int k0 = ks * 64;
    // ---- A: two chunks of 16 fp32 -> cvt -> 2 swizzled ds_write_b128 each
    const float* asrc = Ag + (size_t)arow * 8192 + k0 + ahalf;
    char* abase = smem + arow * 128;
#pragma unroll
    for (int hc = 0; hc < 2; hc++) {
      float f[16];
#pragma unroll
      for (int j = 0; j < 4; j++)
        *(float4*)(f + j * 4) = *(const float4*)(asrc + hc * 16 + j * 4);
      __hip_bfloat16 t[16];
#pragma unroll
      for (int e = 0; e < 16; e++) t[e] = __float2bfloat16(f[e]);
#pragma unroll
      for (int j = 0; j < 2; j++) {
        int c = (ahalf >> 3) + hc * 2 + j; // global chunk index 0..7
        *(bf16x8*)(abase + ((c ^ arx) * 16)) = *(const bf16x8*)(t + j * 8);
      }
    }
    // ---- B: async global->LDS, swizzled on the global side
#pragma unroll
    for (int i = 0; i < 4; i++) {
      const int r = i * 32 + wave * 8 + lrow;
      gl2lds16(Bg + (size_t)r * 512 + k0 + swz,
               smem + 16384 + i * 4096 + wave * 1024 + lane * 16);
    }
    // ---- WgT slice for this k-chunk (gating blocks only)
    if (do_gate) {
      float4 wgq = *(const float4*)(Wgg + (size_t)(k0 + wk) * 16 + wj);
      __hip_bfloat16 wt[4] = {__float2bfloat16(wgq.x), __float2bfloat16(wgq.y),
                              __float2bfloat16(wgq.z), __float2bfloat16(wgq.w)};
#pragma unroll
      for (int i = 0; i < 4; i++)
        *(__hip_bfloat16*)(smem + 36864 + (wj + i) * 144 + wk * 2) = wt[i];
    }
    __syncthreads();
    // ---- MFMA phase for tile ks
#pragma unroll
    for (int hh = 0; hh < 2; hh++) {
      const int co = ((q + hh * 4) ^ xr) * 16;
      bf16x8 av[4], bv[4];
#pragma unroll
      for (int im = 0; im < 4; im++)
        av[im] = *(const bf16x8*)(smem + (wm + im * 16 + l15) * 128 + co);
#pragma unroll
      for (int in = 0; in < 4; in++)
        bv[in] = *(const bf16x8*)(smem + 16384 + (wn + in * 16 + l15) * 128 + co);
#pragma unroll
      for (int im = 0; im < 4; im++)
#pragma unroll
        for (int in = 0; in < 4; in++)
          acc[im][in] = __builtin_amdgcn_mfma_f32_16x16x32_bf16(av[im], bv[in], acc[im][in], 0, 0, 0);
      if (do_gate) {
        bf16x8 wv = *(const bf16x8*)(smem + 36864 + l15 * 144 + (q + hh * 4) * 16);
        accg[0] = __builtin_amdgcn_mfma_f32_16x16x32_bf16(av[gt0], wv, accg[0], 0, 0, 0);
        accg[1] = __builtin_amdgcn_mfma_f32_16x16x32_bf16(av[gt0 + 1], wv, accg[1], 0, 0, 0);
      }
    }
    __syncthreads();
  }

  // ---- gating epilogue: partial[n][row][j]  (R5/R6/R7-proven)
  if (do_gate) {
#pragma unroll
    for (int t2 = 0; t2 < 2; t2++)
#pragma unroll
      for (int r = 0; r < 4; r++) {
        int row = mblk * 128 + wave * 32 + t2 * 16 + q * 4 + r;
        partial[((size_t)n * 2048 + row) * 16 + l15] = accg[t2][r];
      }
  }

  // ---- main epilogue: bias+relu, repack via LDS (stride 144 B), coalesced store
  float bias[4];
#pragma unroll
  for (int in = 0; in < 4; in++)
    bias[in] = b1[n * 512 + nblk * 128 + wn + in * 16 + l15];
  char* epi = smem + wave * 9216;
#pragma unroll
  for (int im = 0; im < 4; im++)
#pragma unroll
    for (int in = 0; in < 4; in++)
#pragma unroll
      for (int r = 0; r < 4; r++) {
        float v = acc[im][in][r] + bias[in];
        v = fmaxf(v, 0.f);
        int rl = im * 16 + q * 4 + r;
        int cl = in * 16 + l15;
        *(__hip_bfloat16*)(epi + rl * 144 + cl * 2) = __float2bfloat16(v);
      }
  __syncthreads();
  __hip_bfloat16* Hg = h + (size_t)(mblk * 128 + wm) * 8192 + n * 512 + nblk * 128 + wn;
#pragma unroll
  for (int it = 0; it < 8; it++) {
    int rl = it * 8 + (lane >> 3);
    int cl = (lane & 7) * 8;
    bf16x8 v = *(const bf16x8*)(epi + rl * 144 + cl * 2);
    *(bf16x8*)(Hg + (size_t)rl * 8192 + cl) = v;
  }
}

// ---------------- GEMM2 + weighted combine (fp32 out) — R4-proven -----------
__global__ __launch_bounds__(256, 4) void gemm2_kernel(
    const __hip_bfloat16* __restrict__ hbuf,
    const __hip_bfloat16* __restrict__ W2t,
    const float* __restrict__ b2,
    const float* __restrict__ probs,
    float* __restrict__ out) {
  __shared__ char smem[32768];
  const int tid = threadIdx.x, lane = tid & 63, wave = tid >> 6;
  int nblk, mblk, n;
  decode_bid(blockIdx.x, nblk, mblk, n);
  const int wm = (wave >> 1) * 64, wn = (wave & 1) * 64;
  const int q = lane >> 4, l15 = lane & 15;
  const int lrow = lane >> 3, lcol = lane & 7;
  const int swz = (lcol ^ lrow) * 8;
  const int xr = l15 & 7;

  const __hip_bfloat16* Ag = hbuf + (size_t)(mblk * 128) * 8192 + n * 512;
  const __hip_bfloat16* Bg = W2t + (size_t)n * 262144 + (size_t)(nblk * 128) * 512;

  f32x4 acc[4][4] = {};
  for (int ks = 0; ks < 8; ks++) {
    const int k0 = ks * 64;
#pragma unroll
    for (int i = 0; i < 4; i++) {
      const int r = i * 32 + wave * 8 + lrow;
      gl2lds16(Ag + (size_t)r * 8192 + k0 + swz, smem + i * 4096 + wave * 1024 + lane * 16);
      gl2lds16(Bg + (size_t)r * 512 + k0 + swz,
               smem + 16384 + i * 4096 + wave * 1024 + lane * 16);
    }
    __syncthreads();
#pragma unroll
    for (int hh = 0; hh < 2; hh++) {
      const int co = ((q + hh * 4) ^ xr) * 16;
      bf16x8 av[4], bv[4];
#pragma unroll
      for (int im = 0; im < 4; im++)
        av[im] = *(const bf16x8*)(smem + (wm + im * 16 + l15) * 128 + co);
#pragma unroll
      for (int in = 0; in < 4; in++)
        bv[in] = *(const bf16x8*)(smem + 16384 + (wn + in * 16 + l15) * 128 + co);
#pragma unroll
      for (int im = 0; im < 4; im++)
#pragma unroll
        for (int in = 0; in < 4; in++)
          acc[im][in] = __builtin_amdgcn_mfma_f32_16x16x32_bf16(av[im], bv[in], acc[im][in], 0, 0, 0);
    }
    __syncthreads();
  }

  float bias[4];
#pragma unroll
  for (int in = 0; in < 4; in++)
    bias[in] = b2[n * 512 + nblk * 128 + wn + in * 16 + l15];
  float* comb = (float*)smem; // [128][8] fp32 (staging LDS reused)
#pragma unroll
  for (int im = 0; im < 4; im++)
#pragma unroll
    for (int r = 0; r < 4; r++) {
      int rl = wm + im * 16 + q * 4 + r; // block-local row 0..127
      float pv = probs[(size_t)(mblk * 128 + rl) * 16 + l15];
#pragma unroll
      for (int in = 0; in < 4; in++) {
        float v = (acc[im][in][r] + bias[in]) * pv;
        v += __shfl_xor(v, 1);
        v += __shfl_xor(v, 2);
        v += __shfl_xor(v, 4);
        v += __shfl_xor(v, 8);
        if (l15 == 0) comb[rl * 8 + (wn >> 4) + in] = v;
      }
    }
  __syncthreads();
  if (tid < 128) {
    float4 v0 = *(const float4*)(comb + tid * 8);
    float4 v1 = *(const float4*)(comb + tid * 8 + 4);
    float* orow = out + (size_t)(mblk * 128 + tid) * 512 + n * 32 + nblk * 8;
    *(float4*)orow = v0;
    *(float4*)(orow + 4) = v1;
  }
}

// ---------------------------------------------------------------------------
extern "C" void kernel_launch(void* const* d_in, const int* in_sizes, int n_in,
                              void* d_out, int out_size, void* d_ws, size_t ws_size,
                              hipStream_t stream) {
  const float* graphs = (const float*)d_in[0];
  const float* W1 = (const float*)d_in[1];
  const float* b1 = (const float*)d_in[2];
  const float* W2 = (const float*)d_in[3];
  const float* b2 = (const float*)d_in[4];
  const float* Wg = (const float*)d_in[5];
  const float* bg = (const float*)d_in[6];
  float* out = (float*)d_out;

  char* ws = (char*)d_ws;
  __hip_bfloat16* W1t = (__hip_bfloat16*)(ws + OFF_W1T);
  __hip_bfloat16* W2t = (__hip_bfloat16*)(ws + OFF_W2T);
  __hip_bfloat16* hb  = (__hip_bfloat16*)(ws + OFF_H);
  float* partial = (float*)(ws + OFF_PART);
  float* probs   = (float*)(ws + OFF_PROB);

  transpose_kernel<<<dim3(16, 16, 32), dim3(32, 8), 0, stream>>>(W1, W2, W1t, W2t);
  gemm1_kernel<<<1024, 256, 0, stream>>>(graphs, W1t, Wg, b1, hb, partial);
  softmax_kernel<<<8, 256, 0, stream>>>(partial, bg, probs, out + 2048 * 512);
  gemm2_kernel<<<1024, 256, 0, stream>>>(hb, W2t, b2, probs, out);
}

// Round 9
// 212.700 us; speedup vs baseline: 1.6049x; 1.4430x over previous
//
#include <hip/hip_runtime.h>
#include <hip/hip_bf16.h>

// ---------------------------------------------------------------------------
// GraphExpert: per-node expert MLPs (16 nodes, 2048 batch, 512 hid) + gating.
// fp32 global I/O, bf16 MFMA compute.
// R9: gemm1 reverted to R4-exact ((256,4), 49us proven). Gating runs as
// DISJOINT blocks (bid>=1024) of the same dispatch (R4 gating body verbatim)
// so it overlaps gemm1's latency stalls without touching the main path's
// register budget (R5/R6/R8 lesson: (256,3) or +AGPRs = 3.5x regression).
// Transpose rewritten vectorized (float4 loads, aligned LDS, bf16x8 stores).
// gemm2 = R4 verbatim. Workspace = proven 52.56 MB envelope.
// ---------------------------------------------------------------------------

typedef __attribute__((ext_vector_type(8))) short bf16x8;   // 8 bf16 = 4 VGPRs
typedef __attribute__((ext_vector_type(4))) float f32x4;    // MFMA C/D frag

// workspace layout (bytes) — identical to R2/R4 (proven safe)
#define OFF_W1T  (0u)          // bf16 [16][512][512]  (8 MB)
#define OFF_W2T  (8388608u)    // bf16 [16][512][512]  (8 MB)
#define OFF_H    (16777216u)   // bf16 [2048][16][512] (33.55 MB)
#define OFF_PART (50331648u)   // fp32 [16][2048][16]  (2 MB)
#define OFF_PROB (52428800u)   // fp32 [2048][16]      (128 KB)

__device__ __forceinline__ void gl2lds16(const void* g, void* l) {
  __builtin_amdgcn_global_load_lds(
      (const __attribute__((address_space(1))) void*)g,
      (__attribute__((address_space(3))) void*)l, 16, 0, 0);
}

__device__ __forceinline__ void cvt16v(const float* __restrict__ src,
                                       bf16x8& lo, bf16x8& hi) {
  float f[16];
  *(float4*)(f + 0)  = *(const float4*)(src + 0);
  *(float4*)(f + 4)  = *(const float4*)(src + 4);
  *(float4*)(f + 8)  = *(const float4*)(src + 8);
  *(float4*)(f + 12) = *(const float4*)(src + 12);
  __hip_bfloat16 t[16];
#pragma unroll
  for (int e = 0; e < 16; e++) t[e] = __float2bfloat16(f[e]);
  lo = *(const bf16x8*)t;
  hi = *(const bf16x8*)(t + 8);
}

// ------ vectorized transpose + cvt: Wt[n][h][k] = bf16(W[n][k][h]) ---------
// 64x64 tiles; float4 global loads, LDS row stride 144 B (16B-aligned),
// bf16x8 coalesced stores.
__global__ __launch_bounds__(256) void transpose_kernel(
    const float* __restrict__ W1, const float* __restrict__ W2,
    __hip_bfloat16* __restrict__ W1t, __hip_bfloat16* __restrict__ W2t) {
  __shared__ char smem[9216]; // 64 h-rows x 144 B (72 bf16, 64 used)
  const int bx = blockIdx.x;              // 0..63: ht(0..7) x kt(0..7)
  const int ht = bx & 7, kt = bx >> 3;
  const int n = blockIdx.y & 15;
  const float* src = (blockIdx.y >> 4) ? W2 : W1;
  __hip_bfloat16* dst = (blockIdx.y >> 4) ? W2t : W1t;
  src += (size_t)n * 262144;
  dst += (size_t)n * 262144;
  const int tid = threadIdx.x;
  const int hq4 = (tid & 15) * 4, kr = tid >> 4; // load: 4 h per thread, 16 k-rows/round
#pragma unroll
  for (int rr = 0; rr < 4; rr++) {
    const int kl = rr * 16 + kr;
    float4 v = *(const float4*)(src + (size_t)(kt * 64 + kl) * 512 + ht * 64 + hq4);
    __hip_bfloat16 t4[4] = {__float2bfloat16(v.x), __float2bfloat16(v.y),
                            __float2bfloat16(v.z), __float2bfloat16(v.w)};
#pragma unroll
    for (int i = 0; i < 4; i++)
      *(__hip_bfloat16*)(smem + (hq4 + i) * 144 + kl * 2) = t4[i];
  }
  __syncthreads();
  const int c8 = tid & 7, hr = tid >> 3; // store: 8 k-chunks x 32 h-rows/round
#pragma unroll
  for (int rr = 0; rr < 2; rr++) {
    const int hl = rr * 32 + hr;
    bf16x8 v = *(const bf16x8*)(smem + hl * 144 + c8 * 16);
    *(bf16x8*)(dst + (size_t)(ht * 64 + hl) * 512 + kt * 64 + c8 * 8) = v;
  }
}

// ---------------- softmax: probs fp32 (ws) + expert_probs fp32 (out) --------
__global__ void softmax_kernel(const float* __restrict__ partial,
                               const float* __restrict__ bg,
                               float* __restrict__ probs,
                               float* __restrict__ probs_out) {
  const int r = blockIdx.x * 256 + threadIdx.x; // 0..2047
  float s[16];
#pragma unroll
  for (int j = 0; j < 16; j++) s[j] = 0.f;
  for (int nn = 0; nn < 16; nn++) {
    const float4* p = (const float4*)(partial + ((size_t)nn * 2048 + r) * 16);
#pragma unroll
    for (int c = 0; c < 4; c++) {
      float4 v = p[c];
      s[c * 4 + 0] += v.x; s[c * 4 + 1] += v.y;
      s[c * 4 + 2] += v.z; s[c * 4 + 3] += v.w;
    }
  }
  float mx = -1e30f;
#pragma unroll
  for (int j = 0; j < 16; j++) { s[j] += bg[j]; mx = fmaxf(mx, s[j]); }
  float sum = 0.f;
#pragma unroll
  for (int j = 0; j < 16; j++) { s[j] = __expf(s[j] - mx); sum += s[j]; }
  float inv = 1.f / sum;
#pragma unroll
  for (int j = 0; j < 16; j++) s[j] *= inv;
  float4* pw = (float4*)(probs + (size_t)r * 16);
  float4* ow = (float4*)(probs_out + (size_t)r * 16);
#pragma unroll
  for (int c = 0; c < 4; c++) {
    float4 v = make_float4(s[c*4], s[c*4+1], s[c*4+2], s[c*4+3]);
    pw[c] = v; ow[c] = v;
  }
}

// block-id remap: the 4 nblk siblings sharing one A-strip sit at bids
// b, b+8, b+16, b+24 (same bid%8 -> same XCD) for L2 reuse of the A strip.
__device__ __forceinline__ void decode_bid(int bid, int& nblk, int& mblk, int& n) {
  int x8 = bid & 7;
  nblk = (bid >> 3) & 3;
  int pair = (bid >> 5) * 8 + x8; // 0..255
  mblk = pair >> 4;
  n = pair & 15;
}

// -------- GEMM1 (R4-exact, bids 0..1023) + gating blocks (bids 1024..2047) --
// Main path: BK=64, XOR-swizzled LDS, A fp32->cvt in staging, B via
// global_load_lds, (256,4), 128 regs — the proven 49us configuration.
// Gating path (R4 gating kernel verbatim): wave-autonomous k-split, small
// register footprint so kernel-wide allocation stays the main path's.
__global__ __launch_bounds__(256, 4) void gemm1_gate_kernel(
    const float* __restrict__ graphs,
    const __hip_bfloat16* __restrict__ W1t,
    const float* __restrict__ Wg,
    const float* __restrict__ b1,
    __hip_bfloat16* __restrict__ h,
    float* __restrict__ partial) {
  __shared__ char smem[36864]; // main: A16K@0,B16K@16384, epi 4x9216@0
                               // gating: per-wave A 4x2048@0, Bt@8192 (16.6K)
  const int tid = threadIdx.x, lane = tid & 63, wave = tid >> 6;
  const int q = lane >> 4, l15 = lane & 15;

  if (blockIdx.x >= 1024) {
    // ================= gating path (R4-proven body) =================
    const int gbid = blockIdx.x - 1024;
    const int n = gbid & 15, rb = gbid >> 4; // 64 row-blocks of 32 rows
    char* Bt = smem + 8192; // Bt[j][k], row stride 1040 B
#pragma unroll
    for (int i = 0; i < 2; i++) {
      int k = i * 256 + tid;
      const float* wr_ = Wg + (size_t)(n * 512 + k) * 16;
      float f[16];
      *(float4*)(f + 0)  = *(const float4*)(wr_ + 0);
      *(float4*)(f + 4)  = *(const float4*)(wr_ + 4);
      *(float4*)(f + 8)  = *(const float4*)(wr_ + 8);
      *(float4*)(f + 12) = *(const float4*)(wr_ + 12);
#pragma unroll
      for (int j = 0; j < 16; j++)
        *(__hip_bfloat16*)(Bt + j * 1040 + k * 2) = __float2bfloat16(f[j]);
    }
    __syncthreads();

    const int arow = lane >> 1, ahalf = (lane & 1) * 16;
    const float* Ag = graphs + (size_t)(rb * 32) * 8192 + n * 512 + wave * 128;
    char* Aw = smem + wave * 2048; // 32 rows x 64 B

    f32x4 acc[2] = {};
    for (int ks = 0; ks < 4; ks++) {
      bf16x8 lo, hi;
      cvt16v(Ag + (size_t)arow * 8192 + ks * 32 + ahalf, lo, hi);
      char* d = Aw + arow * 64 + ahalf * 2;
      *(bf16x8*)d = lo;
      *(bf16x8*)(d + 16) = hi;
      bf16x8 bv = *(const bf16x8*)(Bt + l15 * 1040 + (wave * 128 + ks * 32 + q * 8) * 2);
#pragma unroll
      for (int im = 0; im < 2; im++) {
        bf16x8 av = *(const bf16x8*)(Aw + (im * 16 + l15) * 64 + q * 16);
        acc[im] = __builtin_amdgcn_mfma_f32_16x16x32_bf16(av, bv, acc[im], 0, 0, 0);
      }
    }
#pragma unroll
    for (int im = 0; im < 2; im++)
#pragma unroll
      for (int r = 0; r < 4; r++)
        *(float*)(smem + wave * 2048 + (im * 16 + q * 4 + r) * 64 + l15 * 4) = acc[im][r];
    __syncthreads();
#pragma unroll
    for (int i = 0; i < 2; i++) {
      int c = i * 256 + tid;
      int rrow = c >> 4, j = c & 15;
      float s = 0.f;
#pragma unroll
      for (int w = 0; w < 4; w++) s += *(const float*)(smem + w * 2048 + rrow * 64 + j * 4);
      partial[((size_t)n * 2048 + rb * 32 + rrow) * 16 + j] = s;
    }
    return;
  }

  // ================= main path: R4-exact gemm1 =================
  int nblk, mblk, n;
  decode_bid(blockIdx.x, nblk, mblk, n);
  const int wm = (wave >> 1) * 64, wn = (wave & 1) * 64;
  const int lrow = lane >> 3, lcol = lane & 7;
  const int swz = (lcol ^ lrow) * 8;  // B-side: global chunk for LDS slot lcol
  const int xr = l15 & 7;             // read-side row&7
  const int arow = tid >> 1, ahalf = (tid & 1) * 32; // A staging: row, col-half
  const int arx = arow & 7;

  const float* Ag = graphs + (size_t)(mblk * 128) * 8192 + n * 512;
  const __hip_bfloat16* Bg = W1t + (size_t)n * 262144 + (size_t)(nblk * 128) * 512;

  f32x4 acc[4][4] = {};
  for (int ks = 0; ks < 8; ks++) {
    const int k0 = ks * 64;
    // ---- A: 32 fp32 per thread -> cvt -> 4 swizzled ds_write_b128
    const float* asrc = Ag + (size_t)arow * 8192 + k0 + ahalf;
    float f[32];
#pragma unroll
    for (int j = 0; j < 8; j++) *(float4*)(f + j * 4) = *(const float4*)(asrc + j * 4);
    __hip_bfloat16 t[32];
#pragma unroll
    for (int e = 0; e < 32; e++) t[e] = __float2bfloat16(f[e]);
    char* abase = smem + arow * 128;
#pragma unroll
    for (int j = 0; j < 4; j++) {
      int c = (ahalf >> 3) + j; // global chunk index 0..7
      *(bf16x8*)(abase + ((c ^ arx) * 16)) = *(const bf16x8*)(t + j * 8);
    }
    // ---- B: async global->LDS, swizzled on the global side
#pragma unroll
    for (int i = 0; i < 4; i++) {
      const int r = i * 32 + wave * 8 + lrow;
      gl2lds16(Bg + (size_t)r * 512 + k0 + swz,
               smem + 16384 + i * 4096 + wave * 1024 + lane * 16);
    }
    __syncthreads();
    // ---- MFMA phase for tile ks
#pragma unroll
    for (int hh = 0; hh < 2; hh++) {
      const int co = ((q + hh * 4) ^ xr) * 16;
      bf16x8 av[4], bv[4];
#pragma unroll
      for (int im = 0; im < 4; im++)
        av[im] = *(const bf16x8*)(smem + (wm + im * 16 + l15) * 128 + co);
#pragma unroll
      for (int in = 0; in < 4; in++)
        bv[in] = *(const bf16x8*)(smem + 16384 + (wn + in * 16 + l15) * 128 + co);
#pragma unroll
      for (int im = 0; im < 4; im++)
#pragma unroll
        for (int in = 0; in < 4; in++)
          acc[im][in] = __builtin_amdgcn_mfma_f32_16x16x32_bf16(av[im], bv[in], acc[im][in], 0, 0, 0);
    }
    __syncthreads();
  }

  // ---- epilogue: bias+relu, repack via LDS (stride 144 B), coalesced store
  float bias[4];
#pragma unroll
  for (int in = 0; in < 4; in++)
    bias[in] = b1[n * 512 + nblk * 128 + wn + in * 16 + l15];
  char* epi = smem + wave * 9216;
#pragma unroll
  for (int im = 0; im < 4; im++)
#pragma unroll
    for (int in = 0; in < 4; in++)
#pragma unroll
      for (int r = 0; r < 4; r++) {
        float v = acc[im][in][r] + bias[in];
        v = fmaxf(v, 0.f);
        int rl = im * 16 + q * 4 + r;
        int cl = in * 16 + l15;
        *(__hip_bfloat16*)(epi + rl * 144 + cl * 2) = __float2bfloat16(v);
      }
  __syncthreads();
  __hip_bfloat16* Hg = h + (size_t)(mblk * 128 + wm) * 8192 + n * 512 + nblk * 128 + wn;
#pragma unroll
  for (int it = 0; it < 8; it++) {
    int rl = it * 8 + (lane >> 3);
    int cl = (lane & 7) * 8;
    bf16x8 v = *(const bf16x8*)(epi + rl * 144 + cl * 2);
    *(bf16x8*)(Hg + (size_t)rl * 8192 + cl) = v;
  }
}

// ---------------- GEMM2 + weighted combine (fp32 out) — R4-proven -----------
__global__ __launch_bounds__(256, 4) void gemm2_kernel(
    const __hip_bfloat16* __restrict__ hbuf,
    const __hip_bfloat16* __restrict__ W2t,
    const float* __restrict__ b2,
    const float* __restrict__ probs,
    float* __restrict__ out) {
  __shared__ char smem[32768];
  const int tid = threadIdx.x, lane = tid & 63, wave = tid >> 6;
  int nblk, mblk, n;
  decode_bid(blockIdx.x, nblk, mblk, n);
  const int wm = (wave >> 1) * 64, wn = (wave & 1) * 64;
  const int q = lane >> 4, l15 = lane & 15;
  const int lrow = lane >> 3, lcol = lane & 7;
  const int swz = (lcol ^ lrow) * 8;
  const int xr = l15 & 7;

  const __hip_bfloat16* Ag = hbuf + (size_t)(mblk * 128) * 8192 + n * 512;
  const __hip_bfloat16* Bg = W2t + (size_t)n * 262144 + (size_t)(nblk * 128) * 512;

  f32x4 acc[4][4] = {};
  for (int ks = 0; ks < 8; ks++) {
    const int k0 = ks * 64;
#pragma unroll
    for (int i = 0; i < 4; i++) {
      const int r = i * 32 + wave * 8 + lrow;
      gl2lds16(Ag + (size_t)r * 8192 + k0 + swz, smem + i * 4096 + wave * 1024 + lane * 16);
      gl2lds16(Bg + (size_t)r * 512 + k0 + swz,
               smem + 16384 + i * 4096 + wave * 1024 + lane * 16);
    }
    __syncthreads();
#pragma unroll
    for (int hh = 0; hh < 2; hh++) {
      const int co = ((q + hh * 4) ^ xr) * 16;
      bf16x8 av[4], bv[4];
#pragma unroll
      for (int im = 0; im < 4; im++)
        av[im] = *(const bf16x8*)(smem + (wm + im * 16 + l15) * 128 + co);
#pragma unroll
      for (int in = 0; in < 4; in++)
        bv[in] = *(const bf16x8*)(smem + 16384 + (wn + in * 16 + l15) * 128 + co);
#pragma unroll
      for (int im = 0; im < 4; im++)
#pragma unroll
        for (int in = 0; in < 4; in++)
          acc[im][in] = __builtin_amdgcn_mfma_f32_16x16x32_bf16(av[im], bv[in], acc[im][in], 0, 0, 0);
    }
    __syncthreads();
  }

  float bias[4];
#pragma unroll
  for (int in = 0; in < 4; in++)
    bias[in] = b2[n * 512 + nblk * 128 + wn + in * 16 + l15];
  float* comb = (float*)smem; // [128][8] fp32 (staging LDS reused)
#pragma unroll
  for (int im = 0; im < 4; im++)
#pragma unroll
    for (int r = 0; r < 4; r++) {
      int rl = wm + im * 16 + q * 4 + r; // block-local row 0..127
      float pv = probs[(size_t)(mblk * 128 + rl) * 16 + l15];
#pragma unroll
      for (int in = 0; in < 4; in++) {
        float v = (acc[im][in][r] + bias[in]) * pv;
        v += __shfl_xor(v, 1);
        v += __shfl_xor(v, 2);
        v += __shfl_xor(v, 4);
        v += __shfl_xor(v, 8);
        if (l15 == 0) comb[rl * 8 + (wn >> 4) + in] = v;
      }
    }
  __syncthreads();
  if (tid < 128) {
    float4 v0 = *(const float4*)(comb + tid * 8);
    float4 v1 = *(const float4*)(comb + tid * 8 + 4);
    float* orow = out + (size_t)(mblk * 128 + tid) * 512 + n * 32 + nblk * 8;
    *(float4*)orow = v0;
    *(float4*)(orow + 4) = v1;
  }
}

// ---------------------------------------------------------------------------
extern "C" void kernel_launch(void* const* d_in, const int* in_sizes, int n_in,
                              void* d_out, int out_size, void* d_ws, size_t ws_size,
                              hipStream_t stream) {
  const float* graphs = (const float*)d_in[0];
  const float* W1 = (const float*)d_in[1];
  const float* b1 = (const float*)d_in[2];
  const float* W2 = (const float*)d_in[3];
  const float* b2 = (const float*)d_in[4];
  const float* Wg = (const float*)d_in[5];
  const float* bg = (const float*)d_in[6];
  float* out = (float*)d_out;

  char* ws = (char*)d_ws;
  __hip_bfloat16* W1t = (__hip_bfloat16*)(ws + OFF_W1T);
  __hip_bfloat16* W2t = (__hip_bfloat16*)(ws + OFF_W2T);
  __hip_bfloat16* hb  = (__hip_bfloat16*)(ws + OFF_H);
  float* partial = (float*)(ws + OFF_PART);
  float* probs   = (float*)(ws + OFF_PROB);

  transpose_kernel<<<dim3(64, 32), 256, 0, stream>>>(W1, W2, W1t, W2t);
  gemm1_gate_kernel<<<2048, 256, 0, stream>>>(graphs, W1t, Wg, b1, hb, partial);
  softmax_kernel<<<8, 256, 0, stream>>>(partial, bg, probs, out + 2048 * 512);
  gemm2_kernel<<<1024, 256, 0, stream>>>(hb, W2t, b2, probs, out);
}